// Round 15
// baseline (727.557 us; speedup 1.0000x reference)
//
#include <hip/hip_runtime.h>

// LSTMPINN fused kernel, round 15: the stagger bet at 1-term weights.
// TM=32, 256-thr/4-wave blocks, bounds(256,2) -> 2 INDEPENDENT blocks/CU (two
// barrier domains overlap each other's load-wait + barrier phases; same 8 waves/CU
// as R14). 1-term LSTM (bf16 x bf16) + 2-term dense/output (A hi+lo x bf16 B).
// All weights hi-only row-major in ws. Register demand ~220 <= 256 cap: no spill.

typedef __attribute__((ext_vector_type(8))) short bf16x8;
typedef __attribute__((ext_vector_type(4))) float f32x4;

#define TM 32          // samples per block
#define APAD 8
#define AS (256 + APAD) // A-plane row stride in ushorts

// ws layout (ushort units): ALL matrices bf16 hi-only, row-major.
#define OFF_HH0 0        // 512x128
#define OFF_L1  65536    // 512x256 (cat Wih1|Whh1)
#define OFF_D0  196608   // 256x256 (cols permuted: k<128 -> mean part)
#define OFF_D1  262144
#define OFF_D2  327680
#define OFF_OUT 393216   // 16x256 (rows 4..15 zero)

__device__ __forceinline__ unsigned short f2bf(float x) {
  union { float f; unsigned u; } v; v.f = x;
  unsigned r = v.u + 0x7fffu + ((v.u >> 16) & 1u);   // RNE
  return (unsigned short)(r >> 16);
}
__device__ __forceinline__ float bf2f(unsigned short b) {
  union { unsigned u; float f; } v; v.u = ((unsigned)b) << 16; return v.f;
}
__device__ __forceinline__ float sigm(float v) { return 1.f / (1.f + __expf(-v)); }
__device__ __forceinline__ float tanh_(float v) { return 1.f - 2.f / (__expf(2.f * v) + 1.f); }

// ---------------- prep: all weights -> bf16 hi, row-major ---------------
__global__ void prep_k(const float* __restrict__ Whh0, const float* __restrict__ Wih1,
                       const float* __restrict__ Whh1, const float* __restrict__ Wd0,
                       const float* __restrict__ Wd1, const float* __restrict__ Wd2,
                       const float* __restrict__ Wout, unsigned short* __restrict__ ws) {
  int id = blockIdx.x * 256 + threadIdx.x;
  if (id >= 397312) return;
  float w; int off;
  if (id < 65536) {                       // W_hh_l0 [512][128]
    off = OFF_HH0 + id; w = Whh0[id];
  } else if (id < 196608) {               // B_l1 [512][256] = cat(Wih1, Whh1)
    int i = id - 65536; int r = i >> 8, k = i & 255;
    off = OFF_L1 + i;
    w = (k < 128) ? Wih1[(r << 7) + k] : Whh1[(r << 7) + k - 128];
  } else if (id < 262144) {               // Bd0 [256][256], permute: our k<128 = mean
    int i = id - 196608; int r = i >> 8, k = i & 255;
    off = OFF_D0 + i;
    w = Wd0[(r << 8) + ((k < 128) ? k + 128 : k - 128)];
  } else if (id < 327680) {               // Bd1
    int i = id - 262144; off = OFF_D1 + i; w = Wd1[i];
  } else if (id < 393216) {               // Bd2
    int i = id - 327680; off = OFF_D2 + i; w = Wd2[i];
  } else {                                // Bout [16][256], rows >=4 zero
    int i = id - 393216; int r = i >> 8;
    off = OFF_OUT + i;
    w = (r < 4) ? Wout[i] : 0.f;
  }
  ws[off] = f2bf(w);
}

// ------- 1-term GEMM (LSTM): acc[2][8], B hi-only row-major -------
template <int NT, int KITERS, int UNROLL>
__device__ __forceinline__ void gemmL(const unsigned short* __restrict__ B,
                                      const int ldB, const int* cols,
                                      const unsigned short (*Ah)[AS],
                                      int l16, int quad, f32x4 (&acc)[2][8]) {
  const unsigned short* bp[NT];
#pragma unroll
  for (int n = 0; n < NT; ++n)
    bp[n] = B + (size_t)(cols[n] + l16) * ldB + quad * 8;
  const unsigned short* aph = &Ah[l16][quad * 8];
#pragma unroll UNROLL
  for (int ki = 0; ki < KITERS; ++ki) {
    bf16x8 bh[NT];
#pragma unroll
    for (int n = 0; n < NT; ++n) {
      bh[n] = *(const bf16x8*)(bp[n]);
      bp[n] += 32;
    }
    bf16x8 afh[2];
#pragma unroll
    for (int m = 0; m < 2; ++m)
      afh[m] = *(const bf16x8*)(aph + m * 16 * AS);
#pragma unroll
    for (int n = 0; n < NT; ++n)
#pragma unroll
      for (int m = 0; m < 2; ++m)
        acc[m][n] = __builtin_amdgcn_mfma_f32_16x16x32_bf16(afh[m], bh[n], acc[m][n], 0, 0, 0);
    aph += 32;
  }
}

// ------- 2-term GEMM (dense): acc[2][4], A hi+lo, B hi-only row-major -------
template <int NT, int KITERS, int UNROLL>
__device__ __forceinline__ void gemmD(const unsigned short* __restrict__ B,
                                      const int ldB, const int* cols,
                                      const unsigned short (*Ah)[AS],
                                      const unsigned short (*Al)[AS],
                                      int l16, int quad, f32x4 (&acc)[2][4]) {
  const unsigned short* bp[NT];
#pragma unroll
  for (int n = 0; n < NT; ++n)
    bp[n] = B + (size_t)(cols[n] + l16) * ldB + quad * 8;
  const unsigned short* aph = &Ah[l16][quad * 8];
  const unsigned short* apl = &Al[l16][quad * 8];
#pragma unroll UNROLL
  for (int ki = 0; ki < KITERS; ++ki) {
    bf16x8 bh[NT];
#pragma unroll
    for (int n = 0; n < NT; ++n) {
      bh[n] = *(const bf16x8*)(bp[n]);
      bp[n] += 32;
    }
    bf16x8 afh[2], afl[2];
#pragma unroll
    for (int m = 0; m < 2; ++m) {
      afh[m] = *(const bf16x8*)(aph + m * 16 * AS);
      afl[m] = *(const bf16x8*)(apl + m * 16 * AS);
    }
#pragma unroll
    for (int n = 0; n < NT; ++n)
#pragma unroll
      for (int m = 0; m < 2; ++m)
        acc[m][n] = __builtin_amdgcn_mfma_f32_16x16x32_bf16(afh[m], bh[n], acc[m][n], 0, 0, 0);
#pragma unroll
    for (int n = 0; n < NT; ++n)
#pragma unroll
      for (int m = 0; m < 2; ++m)
        acc[m][n] = __builtin_amdgcn_mfma_f32_16x16x32_bf16(afl[m], bh[n], acc[m][n], 0, 0, 0);
    aph += 32;
    apl += 32;
  }
}

// ---------------- main fused kernel: 1 block = 32 samples, 4 waves -------
__global__ __launch_bounds__(256, 2) void fused_k(
    const float* __restrict__ x, const float* __restrict__ y,
    const float* __restrict__ Wih0, const float* __restrict__ b0,
    const float* __restrict__ b1, const float* __restrict__ bd0,
    const float* __restrict__ bd1, const float* __restrict__ bd2,
    const float* __restrict__ bout, const unsigned short* __restrict__ wsu,
    float* __restrict__ out) {
  // Double-buffered activation planes. Plane p=t&1 holds [h0_t | h1_{t-1}] for iter t.
  // Alo planes only used for dense (written at t=5 and by dense layers).
  __shared__ unsigned short Ahi[2][TM][AS];
  __shared__ unsigned short Alo[2][TM][AS];
  __shared__ float feats[6][TM];

  const int tid = threadIdx.x;
  const int wv = tid >> 6;     // wave 0..3
  const int lane = tid & 63;
  const int quad = lane >> 4;  // 0..3
  const int l16 = lane & 15;
  const int sb = blockIdx.x * TM;

  if (tid < TM) {
    float xn = 2.f * x[sb + tid] - 1.f;
    float yn = 2.f * y[sb + tid] - 1.f;
    feats[0][tid] = xn; feats[1][tid] = yn; feats[2][tid] = xn + yn;
    feats[3][tid] = xn - yn; feats[4][tid] = xn * yn; feats[5][tid] = xn * xn + yn * yn;
  }

  // per-lane weights/biases from global: gate c, subtile s2 -> col 128c+32wv+16s2+l16
  float wih0v[4][2], b0v[4][2], b1v[4][2];
#pragma unroll
  for (int c = 0; c < 4; ++c)
#pragma unroll
    for (int s2 = 0; s2 < 2; ++s2) {
      int j = 128 * c + 32 * wv + 16 * s2 + l16;
      wih0v[c][s2] = Wih0[j]; b0v[c][s2] = b0[j]; b1v[c][s2] = b1[j];
    }

  // per-lane state: [m][r][s2] -> sample s=16m+4quad+r, unit u=32wv+16s2+l16
  float c0[2][4][2], c1[2][4][2], meanh[2][4][2];
#pragma unroll
  for (int m = 0; m < 2; ++m)
#pragma unroll
    for (int r = 0; r < 4; ++r)
#pragma unroll
      for (int s2 = 0; s2 < 2; ++s2) { c0[m][r][s2] = 0.f; c1[m][r][s2] = 0.f; meanh[m][r][s2] = 0.f; }

  int colsL[8];  // n = 2c+s2 -> col block 128c+32wv+16s2 (wave-uniform)
#pragma unroll
  for (int c = 0; c < 4; ++c)
#pragma unroll
    for (int s2 = 0; s2 < 2; ++s2) colsL[2 * c + s2] = 128 * c + 32 * wv + 16 * s2;

  __syncthreads();  // feats visible

  f32x4 acc[2][8];

  // ---- prologue: pw0(t=0): gates = x_0*Wih0 + b0 (no GEMM), h0_0 -> plane 0 (hi) ----
#pragma unroll
  for (int s2 = 0; s2 < 2; ++s2) {
    const int u = 32 * wv + 16 * s2 + l16;
#pragma unroll
    for (int m = 0; m < 2; ++m)
#pragma unroll
      for (int r = 0; r < 4; ++r) {
        const float xf = feats[0][16 * m + 4 * quad + r];
        float iv = sigm(xf * wih0v[0][s2] + b0v[0][s2]);
        float gv = tanh_(xf * wih0v[2][s2] + b0v[2][s2]);
        float ov = sigm(xf * wih0v[3][s2] + b0v[3][s2]);
        float cc = iv * gv;
        c0[m][r][s2] = cc;
        float h = ov * tanh_(cc);
        Ahi[0][16 * m + 4 * quad + r][u] = f2bf(h);
      }
  }

  // ---- main loop: one barrier per t. Plane p = t&1 holds [h0_t | h1_{t-1}]. ----
#pragma unroll 1
  for (int t = 0; t < 6; ++t) {
    const int p = t & 1;
    const int pn = p ^ 1;
    __syncthreads();  // h0_t (and h1_{t-1}) visible in plane p; WAR for plane pn writes

    // gemm1(t): gates1 = [h0_t ; h1_{t-1}] @ [Wih1;Whh1]^T + b1  (1-term)
#pragma unroll
    for (int m = 0; m < 2; ++m)
#pragma unroll
      for (int c = 0; c < 4; ++c)
#pragma unroll
        for (int s2 = 0; s2 < 2; ++s2)
#pragma unroll
          for (int r = 0; r < 4; ++r) acc[m][2 * c + s2][r] = b1v[c][s2];
    if (t == 0)
      gemmL<8, 4, 1>(wsu + OFF_L1, 256, colsL, Ahi[p], l16, quad, acc);
    else
      gemmL<8, 8, 2>(wsu + OFF_L1, 256, colsL, Ahi[p], l16, quad, acc);

    // pw1(t): h1_t -> plane pn [128:256) (hi; +lo at t=5); mean at t=5 -> pn [0:128)
#pragma unroll
    for (int m = 0; m < 2; ++m)
#pragma unroll
      for (int r = 0; r < 4; ++r) {
        const int s = 16 * m + 4 * quad + r;
#pragma unroll
        for (int s2 = 0; s2 < 2; ++s2) {
          float iv = sigm(acc[m][0 + s2][r]);
          float fv = sigm(acc[m][2 + s2][r]);
          float gv = tanh_(acc[m][4 + s2][r]);
          float ov = sigm(acc[m][6 + s2][r]);
          float cc = fv * c1[m][r][s2] + iv * gv;
          c1[m][r][s2] = cc;
          float h = ov * tanh_(cc);
          const int u = 32 * wv + 16 * s2 + l16;
          unsigned short hh = f2bf(h);
          Ahi[pn][s][128 + u] = hh;
          float mn = meanh[m][r][s2] + h;
          meanh[m][r][s2] = mn;
          if (t == 5) {
            Alo[pn][s][128 + u] = f2bf(h - bf2f(hh));  // "last" lo for dense 2-term
            mn *= (1.f / 6.f);
            unsigned short mh = f2bf(mn);
            Ahi[pn][s][u] = mh;
            Alo[pn][s][u] = f2bf(mn - bf2f(mh));
          }
        }
      }

    if (t < 5) {
      // gemm0(t+1): gates0 = x_{t+1}*Wih0 + b0 (C-init) + h0_t @ Whh0^T  (1-term)
#pragma unroll
      for (int m = 0; m < 2; ++m)
#pragma unroll
        for (int r = 0; r < 4; ++r) {
          const float xf = feats[t + 1][16 * m + 4 * quad + r];
#pragma unroll
          for (int c = 0; c < 4; ++c)
#pragma unroll
            for (int s2 = 0; s2 < 2; ++s2)
              acc[m][2 * c + s2][r] = xf * wih0v[c][s2] + b0v[c][s2];
        }
      gemmL<8, 4, 1>(wsu + OFF_HH0, 128, colsL, Ahi[p], l16, quad, acc);

      // pw0(t+1): h0_{t+1} -> plane pn [0:128) (hi only)
#pragma unroll
      for (int m = 0; m < 2; ++m)
#pragma unroll
        for (int r = 0; r < 4; ++r) {
          const int s = 16 * m + 4 * quad + r;
#pragma unroll
          for (int s2 = 0; s2 < 2; ++s2) {
            float iv = sigm(acc[m][0 + s2][r]);
            float fv = sigm(acc[m][2 + s2][r]);
            float gv = tanh_(acc[m][4 + s2][r]);
            float ov = sigm(acc[m][6 + s2][r]);
            float cc = fv * c0[m][r][s2] + iv * gv;
            c0[m][r][s2] = cc;
            float h = ov * tanh_(cc);
            Ahi[pn][s][32 * wv + 16 * s2 + l16] = f2bf(h);
          }
        }
    }
  }

  // ---- dense head: 3 layers (2-term); L0 reads plane0=[mean|last] ----
  int colsD[4];
#pragma unroll
  for (int n = 0; n < 4; ++n) colsD[n] = 64 * wv + 16 * n;

#pragma unroll 1
  for (int layer = 0; layer < 3; ++layer) {
    const int base = (layer == 0) ? OFF_D0 : ((layer == 1) ? OFF_D1 : OFF_D2);
    const float* bd = (layer == 0) ? bd0 : ((layer == 1) ? bd1 : bd2);
    const int sp = layer & 1;   // read plane 0,1,0
    const int dp = sp ^ 1;
    f32x4 accd[2][4];
#pragma unroll
    for (int n = 0; n < 4; ++n) {
      const float bv = bd[colsD[n] + l16];
#pragma unroll
      for (int m = 0; m < 2; ++m)
#pragma unroll
        for (int r = 0; r < 4; ++r) accd[m][n][r] = bv;
    }
    __syncthreads();  // prev writes visible; prev reads of dp done (WAR)
    gemmD<4, 8, 2>(wsu + base, 256, colsD, Ahi[sp], Alo[sp], l16, quad, accd);
#pragma unroll
    for (int m = 0; m < 2; ++m)
#pragma unroll
      for (int r = 0; r < 4; ++r) {
        const int s = 16 * m + 4 * quad + r;
#pragma unroll
        for (int n = 0; n < 4; ++n) {
          const int col = colsD[n] + l16;
          float a = tanh_(accd[m][n][r]);
          unsigned short ah = f2bf(a);
          Ahi[dp][s][col] = ah;
          Alo[dp][s][col] = f2bf(a - bf2f(ah));
        }
      }
  }
  __syncthreads();

  // ---- output layer (2-term): waves 0..1 handle m-tile wv; read plane 1 ----
  if (wv < 2) {
    f32x4 oacc = {0.f, 0.f, 0.f, 0.f};
    const unsigned short* bp = wsu + OFF_OUT + (size_t)l16 * 256 + quad * 8;
    const unsigned short* aph = &Ahi[1][16 * wv + l16][quad * 8];
    const unsigned short* apl = &Alo[1][16 * wv + l16][quad * 8];
#pragma unroll 1
    for (int ki = 0; ki < 8; ++ki) {
      bf16x8 ah = *(const bf16x8*)aph;
      bf16x8 al = *(const bf16x8*)apl;
      bf16x8 bh = *(const bf16x8*)bp;
      oacc = __builtin_amdgcn_mfma_f32_16x16x32_bf16(ah, bh, oacc, 0, 0, 0);
      oacc = __builtin_amdgcn_mfma_f32_16x16x32_bf16(al, bh, oacc, 0, 0, 0);
      aph += 32; apl += 32; bp += 32;
    }
    float bo = (l16 < 4) ? bout[l16] : 0.f;
#pragma unroll
    for (int r = 0; r < 4; ++r) {
      if (l16 < 4) {
        int s = sb + 16 * wv + 4 * quad + r;
        out[s * 4 + l16] = oacc[r] + bo;
      }
    }
  }
}

extern "C" void kernel_launch(void* const* d_in, const int* in_sizes, int n_in,
                              void* d_out, int out_size, void* d_ws, size_t ws_size,
                              hipStream_t stream) {
  (void)in_sizes; (void)n_in; (void)out_size; (void)ws_size;
  const float* x    = (const float*)d_in[0];
  const float* y    = (const float*)d_in[1];
  const float* Wih0 = (const float*)d_in[2];
  const float* Whh0 = (const float*)d_in[3];
  const float* b0   = (const float*)d_in[4];
  const float* Wih1 = (const float*)d_in[5];
  const float* Whh1 = (const float*)d_in[6];
  const float* b1   = (const float*)d_in[7];
  const float* Wd0  = (const float*)d_in[8];
  const float* bd0  = (const float*)d_in[9];
  const float* Wd1  = (const float*)d_in[10];
  const float* bd1  = (const float*)d_in[11];
  const float* Wd2  = (const float*)d_in[12];
  const float* bd2  = (const float*)d_in[13];
  const float* Wout = (const float*)d_in[14];
  const float* bout = (const float*)d_in[15];
  unsigned short* ws = (unsigned short*)d_ws;
  float* out = (float*)d_out;

  prep_k<<<dim3(1552), dim3(256), 0, stream>>>(Whh0, Wih1, Whh1, Wd0, Wd1, Wd2, Wout, ws);
  fused_k<<<dim3(65536 / TM), dim3(256), 0, stream>>>(x, y, Wih0, b0, b1, bd0, bd1, bd2,
                                                      bout, ws, out);
}